// Round 17
// baseline (189.744 us; speedup 1.0000x reference)
//
#include <hip/hip_runtime.h>
#include <math.h>

// TemporalWasteGNN: 3x GCNConv (symmetric-norm, self-loops) -> 2x LSTM(seq=1, h0=c0=0)
// -> two MLP heads. fp32 I/O, bf16 intermediate features.
//
// R17: single change vs R16: gather pipeline deepened 4 -> 8 in agg_row
//      (8 outstanding row loads per node chain; deg=16 -> 2 big iterations).
//      FP order preserved (8-deep, then 4-deep, then scalar tail in j order)
//      -> bit-identical. Applies to agg_kernel + both fused_agg_transform.
// R16 512-thread fused agg+transform, R10 packed CSR build, R13 prepped
// slabs, R7 native transcendentals, R13 tail — all retained.

typedef unsigned int  u32;
typedef unsigned short u16;
typedef short bfrag  __attribute__((ext_vector_type(8)));   // 8 bf16 (4 VGPRs)
typedef float f32x4  __attribute__((ext_vector_type(4)));

#define LOG2E 1.44269504088896f
static __device__ __forceinline__ float fast_sigmoid(float x){
  float t = __builtin_amdgcn_exp2f(-x * LOG2E);
  return __builtin_amdgcn_rcpf(1.f + t);
}
static __device__ __forceinline__ float fast_tanh(float x){
  float t = __builtin_amdgcn_exp2f(x * (2.f * LOG2E));
  return 1.f - 2.f * __builtin_amdgcn_rcpf(t + 1.f);
}
static __device__ __forceinline__ float bf2f(u16 u){ return __uint_as_float(((u32)u)<<16); }
static __device__ __forceinline__ u16   f2bf(float f){
  u32 x = __float_as_uint(f);
  return (u16)((x + 0x7fffu + ((x>>16)&1u)) >> 16);   // round-to-nearest-even
}

#define MAXBK 512   // buckets of 256 dst nodes; N <= 131072 (src must fit 24 bits)

// ---------------- bucketed CSR build ----------------
__global__ __launch_bounds__(512) void bucket_hist_kernel(const int* __restrict__ dstA,
                                                          int* __restrict__ bhist, int E){
  __shared__ int h[MAXBK];
  for (int i=threadIdx.x; i<MAXBK; i+=512) h[i]=0;
  __syncthreads();
  const int base = blockIdx.x*8192;
  #pragma unroll
  for (int j=0;j<16;++j){
    int e = base + j*512 + threadIdx.x;
    if (e < E) atomicAdd(&h[dstA[e]>>8], 1);
  }
  __syncthreads();
  for (int i=threadIdx.x; i<MAXBK; i+=512) if (h[i]) atomicAdd(&bhist[i], h[i]);
}

__global__ __launch_bounds__(512) void bucket_scan_kernel(const int* __restrict__ bhist,
                                                          int* __restrict__ bcur,
                                                          int* __restrict__ bstart){
  __shared__ int ts[MAXBK];
  int v = bhist[threadIdx.x];
  ts[threadIdx.x] = v; __syncthreads();
  for (int off=1; off<MAXBK; off<<=1){
    int t = (threadIdx.x>=off) ? ts[threadIdx.x-off] : 0;
    __syncthreads();
    ts[threadIdx.x] += t;
    __syncthreads();
  }
  int ex = ts[threadIdx.x] - v;
  bcur[threadIdx.x]   = ex;
  bstart[threadIdx.x] = ex;
  if (threadIdx.x == MAXBK-1) bstart[MAXBK] = ts[threadIdx.x];   // = E
}

__global__ __launch_bounds__(512) void bin_kernel(const int* __restrict__ srcA,
                                                  const int* __restrict__ dstA,
                                                  int* __restrict__ bcur,
                                                  u32* __restrict__ packed, int E){
  __shared__ int h[MAXBK];
  __shared__ int basev[MAXBK];
  for (int i=threadIdx.x; i<MAXBK; i+=512) h[i]=0;
  __syncthreads();
  const int base = blockIdx.x*8192;
  int br[16]; int dv[16];
  #pragma unroll
  for (int j=0;j<16;++j){
    int e = base + j*512 + threadIdx.x;
    if (e < E){
      int d = dstA[e]; int b = d>>8;
      int r = atomicAdd(&h[b], 1);
      br[j] = (b<<16) | r;                 // b<512 (9b) | r<8192 (13b)
      dv[j] = d;
    } else br[j] = -1;
  }
  __syncthreads();
  for (int i=threadIdx.x; i<MAXBK; i+=512){
    int c = h[i];
    basev[i] = c ? atomicAdd(&bcur[i], c) : 0;
  }
  __syncthreads();
  #pragma unroll
  for (int j=0;j<16;++j){
    if (br[j] >= 0){
      int e = base + j*512 + threadIdx.x;
      int pos = basev[br[j]>>16] + (br[j] & 0xffff);
      packed[pos] = (u32)srcA[e] | ((u32)(dv[j] & 255) << 24);
    }
  }
}

__global__ __launch_bounds__(512) void bucket_finalize_kernel(
    const u32* __restrict__ packed, const int* __restrict__ bstart,
    int* __restrict__ offs, float* __restrict__ dinv,
    int* __restrict__ csr, int n, int E){
  __shared__ int cnt[256];
  __shared__ int sc[256];
  __shared__ int cur[256];
  const int b = blockIdx.x;
  const int start = bstart[b], end = bstart[b+1];
  for (int i=threadIdx.x; i<256; i+=512){ cnt[i]=0; cur[i]=0; }
  __syncthreads();
  for (int e = start + threadIdx.x; e < end; e += 512)
    atomicAdd(&cnt[packed[e] >> 24], 1);
  __syncthreads();
  if (threadIdx.x < 256) sc[threadIdx.x] = cnt[threadIdx.x];
  __syncthreads();
  for (int off=1; off<256; off<<=1){
    int t = 0;
    if (threadIdx.x < 256 && threadIdx.x >= off) t = sc[threadIdx.x-off];
    __syncthreads();
    if (threadIdx.x < 256) sc[threadIdx.x] += t;
    __syncthreads();
  }
  if (threadIdx.x < 256){
    int ex = sc[threadIdx.x] - cnt[threadIdx.x];      // exclusive
    sc[threadIdx.x] = ex;
    int node = b*256 + threadIdx.x;
    if (node < n){
      offs[node] = start + ex;
      dinv[node] = rsqrtf((float)(cnt[threadIdx.x] + 1));
    }
  }
  if (b == 0 && threadIdx.x == 0) offs[n] = E;
  __syncthreads();
  for (int e = start + threadIdx.x; e < end; e += 512){
    u32 v = packed[e];
    int loc = v >> 24;
    int pos = start + sc[loc] + atomicAdd(&cur[loc], 1);
    csr[pos] = (int)(v & 0xFFFFFFu);
  }
}

// fallback (N too large for bucketing) -------------
__global__ void count_kernel(const int* __restrict__ dsts, int* __restrict__ deg, int E){
  int e = blockIdx.x*256 + threadIdx.x;
  if (e < E) atomicAdd(&deg[dsts[e]], 1);
}
__global__ void fill_kernel(const int* __restrict__ ei, int* __restrict__ cursor,
                            int* __restrict__ csr, int E){
  int e = blockIdx.x*256 + threadIdx.x;
  if (e < E){
    int d = ei[E + e];
    int pos = atomicAdd(&cursor[d], 1);
    csr[pos] = ei[e];
  }
}

__global__ void scan_reduce_kernel(const int* __restrict__ deg, int* __restrict__ bsums, int n){
  __shared__ int sd[256];
  int base = blockIdx.x*1024 + threadIdx.x*4;
  int s = 0;
  #pragma unroll
  for (int j=0;j<4;++j){ int idx=base+j; if (idx<n) s += deg[idx]; }
  sd[threadIdx.x] = s; __syncthreads();
  for (int off=128; off>0; off>>=1){
    if (threadIdx.x < off) sd[threadIdx.x] += sd[threadIdx.x+off];
    __syncthreads();
  }
  if (threadIdx.x==0) bsums[blockIdx.x] = sd[0];
}

__global__ void scan_block_kernel(const int* __restrict__ bsums, int* __restrict__ boffs, int nb){
  __shared__ int ts[128];
  if (nb <= 128){
    int v = (threadIdx.x < nb) ? bsums[threadIdx.x] : 0;
    ts[threadIdx.x] = v; __syncthreads();
    for (int off=1; off<128; off<<=1){
      int t = (threadIdx.x>=off) ? ts[threadIdx.x-off] : 0;
      __syncthreads();
      ts[threadIdx.x] += t;
      __syncthreads();
    }
    if (threadIdx.x < nb) boffs[threadIdx.x] = ts[threadIdx.x] - v;
  } else if (threadIdx.x==0){
    int run=0;
    for (int b=0;b<nb;++b){ int t=bsums[b]; boffs[b]=run; run+=t; }
  }
}

__global__ void scan_final_kernel(const int* __restrict__ deg, const int* __restrict__ boffs,
                                  int* __restrict__ offs, int n, int E){
  __shared__ int ts[256];
  int base = blockIdx.x*1024 + threadIdx.x*4;
  int v[4]; int s=0;
  #pragma unroll
  for (int j=0;j<4;++j){ int idx=base+j; v[j] = (idx<n) ? deg[idx] : 0; s += v[j]; }
  ts[threadIdx.x] = s; __syncthreads();
  for (int off=1; off<256; off<<=1){
    int t = (threadIdx.x>=off) ? ts[threadIdx.x-off] : 0;
    __syncthreads();
    ts[threadIdx.x] += t;
    __syncthreads();
  }
  int excl = boffs[blockIdx.x] + (threadIdx.x ? ts[threadIdx.x-1] : 0);
  #pragma unroll
  for (int j=0;j<4;++j){ int idx=base+j; if (idx<n){ offs[idx]=excl; excl+=v[j]; } }
  if (blockIdx.x==0 && threadIdx.x==0) offs[n] = E;
}

__global__ void dinv_kernel(const int* __restrict__ deg, const int* __restrict__ offs,
                            int* __restrict__ cursor, float* __restrict__ dinv, int n){
  int i = blockIdx.x*256 + threadIdx.x;
  if (i < n){
    dinv[i] = rsqrtf((float)(deg[i] + 1));
    cursor[i] = offs[i];
  }
}

// ---------------- run-once weight prep (tail + GCN) ----------------
__global__ void prep_tail_kernel(const float* __restrict__ Wih0, const float* __restrict__ Wih1,
                                 const float* __restrict__ Wv1,  const float* __restrict__ Wt1,
                                 const float* __restrict__ Wv2,  const float* __restrict__ Wt2,
                                 const float* __restrict__ bih0, const float* __restrict__ bhh0,
                                 const float* __restrict__ bih1, const float* __restrict__ bhh1,
                                 const float* __restrict__ Wg1,  const float* __restrict__ Wg2,
                                 const float* __restrict__ Wg3,
                                 u16* __restrict__ wbuf, float* __restrict__ bbuf,
                                 u16* __restrict__ wgcn, int* __restrict__ bhist){
  int tid = blockIdx.x*256 + threadIdx.x;
  if (tid < 6144){                                  // Wih0 hi/lo, [k/8][96][8]
    int kg = tid / 768, rem = tid % 768;
    int j = rem >> 3, k = kg*8 + (rem & 7);
    int row = (j < 32) ? j : j + 32;
    float w = Wih0[row*64 + k];
    u16 hi = f2bf(w);
    wbuf[tid] = hi;
    wbuf[6144 + tid] = f2bf(w - bf2f(hi));
  } else if (tid < 9216){                           // Wih1, [k/8][96][8]
    int t = tid - 6144;
    int kg = t / 768, rem = t % 768;
    int j = rem >> 3, k = kg*8 + (rem & 7);
    int row = (j < 32) ? j : j + 32;
    wbuf[12288 + t] = f2bf(Wih1[row*32 + k]);
  } else if (tid < 11264){                          // Wv1|Wt1, [k/8][64][8]
    int t = tid - 9216;
    int kg = t / 512, rem = t % 512;
    int j = rem >> 3, k = kg*8 + (rem & 7);
    float v = (j < 32) ? Wv1[k*32 + j] : Wt1[k*32 + (j-32)];
    wbuf[15360 + t] = f2bf(v);
  } else if (tid < 11360){                          // b0 (i,g,o combined)
    int t = tid - 11264;
    int row = (t < 32) ? t : t + 32;
    bbuf[t] = bih0[row] + bhh0[row];
  } else if (tid < 11456){                          // b1
    int t = tid - 11360;
    int row = (t < 32) ? t : t + 32;
    bbuf[96 + t] = bih1[row] + bhh1[row];
  } else if (tid < 12480){                          // BV/BT lane fragments (K=32)
    int t = tid - 11456;
    int slab = t >> 9, within = t & 511;
    int lane = within >> 3, j = within & 7;
    int cc = lane & 15, gg = lane >> 4;
    float v;
    if (slab == 0) v = (cc == 0) ? Wv2[gg*8 + j] : 0.f;
    else           v = (cc < 10) ? Wt2[(gg*8 + j)*10 + cc] : 0.f;
    wbuf[17408 + slab*512 + within] = f2bf(v);
  } else if (tid < 12992){                          // zero bhist
    bhist[tid - 12480] = 0;
  } else if (tid < 21184){                          // W1 (128x64) -> G1
    int t = tid - 12992;
    int kg = t >> 9, rem = t & 511;
    int j = rem >> 3, k = kg*8 + (rem & 7);
    wgcn[t] = f2bf(Wg1[k*64 + j]);
  } else if (tid < 25280){                          // W2 (64x64) -> G2
    int t = tid - 21184;
    int kg = t >> 9, rem = t & 511;
    int j = rem >> 3, k = kg*8 + (rem & 7);
    wgcn[8192 + t] = f2bf(Wg2[k*64 + j]);
  } else if (tid < 29376){                          // W3 (64x64) -> G3
    int t = tid - 25280;
    int kg = t >> 9, rem = t & 511;
    int j = rem >> 3, k = kg*8 + (rem & 7);
    wgcn[12288 + t] = f2bf(Wg3[k*64 + j]);
  }
}

// ---------------- gather-agg helper: acc over adjacency, 8-deep pipelined ----------------
// FP order identical to serial (8-deep block, 4-deep block, scalar tail, all in j order).
static __device__ __forceinline__ uint4 agg_row(const uint4* __restrict__ H,
                                                const float* __restrict__ dinv,
                                                const int* __restrict__ offs,
                                                const int* __restrict__ csr,
                                                const float* __restrict__ bias,
                                                int node, int c8){
  float acc[8];
  #pragma unroll
  for (int i=0;i<8;++i) acc[i]=0.f;
  const int beg = offs[node], end = offs[node+1];
  #define ACC8(v) do{ \
    acc[0] += __uint_as_float((v).x<<16); acc[1] += __uint_as_float((v).x & 0xffff0000u); \
    acc[2] += __uint_as_float((v).y<<16); acc[3] += __uint_as_float((v).y & 0xffff0000u); \
    acc[4] += __uint_as_float((v).z<<16); acc[5] += __uint_as_float((v).z & 0xffff0000u); \
    acc[6] += __uint_as_float((v).w<<16); acc[7] += __uint_as_float((v).w & 0xffff0000u); }while(0)
  int j = beg;
  for (; j + 8 <= end; j += 8){
    int s0 = csr[j],   s1 = csr[j+1], s2 = csr[j+2], s3 = csr[j+3];
    int s4 = csr[j+4], s5 = csr[j+5], s6 = csr[j+6], s7 = csr[j+7];
    uint4 v0 = H[(size_t)s0*8 + c8];
    uint4 v1 = H[(size_t)s1*8 + c8];
    uint4 v2 = H[(size_t)s2*8 + c8];
    uint4 v3 = H[(size_t)s3*8 + c8];
    uint4 v4 = H[(size_t)s4*8 + c8];
    uint4 v5 = H[(size_t)s5*8 + c8];
    uint4 v6 = H[(size_t)s6*8 + c8];
    uint4 v7 = H[(size_t)s7*8 + c8];
    ACC8(v0); ACC8(v1); ACC8(v2); ACC8(v3);
    ACC8(v4); ACC8(v5); ACC8(v6); ACC8(v7);
  }
  for (; j + 4 <= end; j += 4){
    int s0 = csr[j], s1 = csr[j+1], s2 = csr[j+2], s3 = csr[j+3];
    uint4 v0 = H[(size_t)s0*8 + c8];
    uint4 v1 = H[(size_t)s1*8 + c8];
    uint4 v2 = H[(size_t)s2*8 + c8];
    uint4 v3 = H[(size_t)s3*8 + c8];
    ACC8(v0); ACC8(v1); ACC8(v2); ACC8(v3);
  }
  for (; j < end; ++j){
    int src = csr[j];
    uint4 v = H[(size_t)src*8 + c8];
    ACC8(v);
  }
  #undef ACC8
  uint4 sv = H[(size_t)node*8 + c8];       // self-loop (already * dinv[node])
  float sf[8];
  sf[0]=__uint_as_float(sv.x<<16); sf[1]=__uint_as_float(sv.x & 0xffff0000u);
  sf[2]=__uint_as_float(sv.y<<16); sf[3]=__uint_as_float(sv.y & 0xffff0000u);
  sf[4]=__uint_as_float(sv.z<<16); sf[5]=__uint_as_float(sv.z & 0xffff0000u);
  sf[6]=__uint_as_float(sv.w<<16); sf[7]=__uint_as_float(sv.w & 0xffff0000u);
  float4 b0 = ((const float4*)bias)[c8*2];
  float4 b1 = ((const float4*)bias)[c8*2+1];
  const float dv = dinv[node];
  float o[8];
  o[0]=fmaxf(fmaf(acc[0]+sf[0],dv,b0.x),0.f); o[1]=fmaxf(fmaf(acc[1]+sf[1],dv,b0.y),0.f);
  o[2]=fmaxf(fmaf(acc[2]+sf[2],dv,b0.z),0.f); o[3]=fmaxf(fmaf(acc[3]+sf[3],dv,b0.w),0.f);
  o[4]=fmaxf(fmaf(acc[4]+sf[4],dv,b1.x),0.f); o[5]=fmaxf(fmaf(acc[5]+sf[5],dv,b1.y),0.f);
  o[6]=fmaxf(fmaf(acc[6]+sf[6],dv,b1.z),0.f); o[7]=fmaxf(fmaf(acc[7]+sf[7],dv,b1.w),0.f);
  uint4 w;
  w.x = (u32)f2bf(o[0]) | ((u32)f2bf(o[1])<<16);
  w.y = (u32)f2bf(o[2]) | ((u32)f2bf(o[3])<<16);
  w.z = (u32)f2bf(o[4]) | ((u32)f2bf(o[5])<<16);
  w.w = (u32)f2bf(o[6]) | ((u32)f2bf(o[7])<<16);
  return w;
}

// ---------------- standalone agg (layer 3): 8 nodes/wave, 8-deep pipelined ----------------
__global__ void agg_kernel(const u16* __restrict__ Hts, const float* __restrict__ dinv,
                           const int* __restrict__ offs, const int* __restrict__ csr,
                           const float* __restrict__ bias, u16* __restrict__ Hout, int n){
  const int lane = threadIdx.x & 63;
  const int wv   = threadIdx.x >> 6;
  const int s    = lane >> 3;
  const int c8   = lane & 7;
  const int node = blockIdx.x*32 + wv*8 + s;
  if (node >= n) return;
  const uint4* __restrict__ H = (const uint4*)Hts;
  uint4 w = agg_row(H, dinv, offs, csr, bias, node, c8);
  ((uint4*)Hout)[(size_t)node*8 + c8] = w;
}

// ---------------- GCN transform via MFMA (layer 1; W from prepped slab) ----------------
template<int KD, typename TIN>
__global__ __launch_bounds__(256) void transform_mfma(const TIN* __restrict__ X,
                                                      const u16* __restrict__ WG,
                                                      const float* __restrict__ dinv,
                                                      u16* __restrict__ Y, int n){
  constexpr int XLD = KD + 8;
  __shared__ u16 Xl[128*XLD];
  __shared__ float Dl[128];
  const int tid  = threadIdx.x;
  const int base = blockIdx.x*128;

  if (tid < 128){
    int nd = base + tid;
    Dl[tid] = (nd < n) ? dinv[nd] : 0.f;
  }
  if constexpr (sizeof(TIN)==4){
    #pragma unroll
    for (int j = 0; j < (128*KD)/1024; ++j){
      int e4   = tid + j*256;
      int elem = e4*4;
      int row  = elem / KD, k = elem % KD;
      int gn   = base + row;
      uint2 w2 = make_uint2(0u, 0u);
      if (gn < n){
        float4 v = ((const float4*)X)[(size_t)gn*(KD/4) + (k>>2)];
        w2.x = (u32)f2bf(v.x) | ((u32)f2bf(v.y)<<16);
        w2.y = (u32)f2bf(v.z) | ((u32)f2bf(v.w)<<16);
      }
      *((uint2*)&Xl[row*XLD + k]) = w2;
    }
  } else {
    #pragma unroll
    for (int j = 0; j < (128*KD)/1024; ++j){
      int e4   = tid + j*256;
      int elem = e4*4;
      int row  = elem / KD, k = elem % KD;
      int gn   = base + row;
      uint2 v = make_uint2(0u, 0u);
      if (gn < n) v = *((const uint2*)(X + (size_t)gn*KD + k));
      *((uint2*)&Xl[row*XLD + k]) = v;
    }
  }

  const int lane = tid & 63, wv = tid >> 6;
  const int c = lane & 15, g = lane >> 4;

  bfrag wf[KD/32][4];
  #pragma unroll
  for (int kk=0; kk<KD/32; ++kk)
    #pragma unroll
    for (int nt=0; nt<4; ++nt)
      wf[kk][nt] = *((const bfrag*)&WG[((kk*4+g)<<9) + ((nt*16+c)<<3)]);

  __syncthreads();                   // Xl ready

  f32x4 acc[2][4];
  #pragma unroll
  for (int rs=0;rs<2;++rs)
    #pragma unroll
    for (int nt=0;nt<4;++nt)
      acc[rs][nt] = (f32x4){0.f,0.f,0.f,0.f};

  #pragma unroll
  for (int kk=0; kk<KD/32; ++kk){
    bfrag a0 = *((const bfrag*)&Xl[(wv*32      + c)*XLD + kk*32 + g*8]);
    bfrag a1 = *((const bfrag*)&Xl[(wv*32 + 16 + c)*XLD + kk*32 + g*8]);
    #pragma unroll
    for (int nt=0; nt<4; ++nt){
      acc[0][nt] = __builtin_amdgcn_mfma_f32_16x16x32_bf16(a0, wf[kk][nt], acc[0][nt], 0,0,0);
      acc[1][nt] = __builtin_amdgcn_mfma_f32_16x16x32_bf16(a1, wf[kk][nt], acc[1][nt], 0,0,0);
    }
  }

  #pragma unroll
  for (int rs=0;rs<2;++rs){
    int nl0 = wv*32 + rs*16 + g*4;
    #pragma unroll
    for (int r=0;r<4;++r){
      int node = base + nl0 + r;
      if (node < n){
        float dv = Dl[nl0 + r];
        #pragma unroll
        for (int nt=0;nt<4;++nt)
          Y[(size_t)node*64 + nt*16 + c] = f2bf(acc[rs][nt][r] * dv);
      }
    }
  }
}

// ---------------- fused agg + transform (layers 2,3 input), 512 threads ----------------
__global__ __launch_bounds__(512) void fused_agg_transform(
    const u16* __restrict__ Hsrc, const float* __restrict__ dinv,
    const int* __restrict__ offs, const int* __restrict__ csr,
    const float* __restrict__ bias, const u16* __restrict__ WG,
    u16* __restrict__ Y, int n){
  constexpr int XLD = 72;
  __shared__ u16 Xl[128*XLD];
  __shared__ float Dl[128];
  const int tid  = threadIdx.x;
  const int base = blockIdx.x*128;
  const int lane = tid & 63, wv = tid >> 6;   // wv in 0..7

  if (tid < 128){
    int nd = base + tid;
    Dl[tid] = (nd < n) ? dinv[nd] : 0.f;
  }

  // ---- phase A: aggregate this block's 128 nodes into Xl ----
  {
    const int s  = lane >> 3;
    const int c8 = lane & 7;
    const uint4* __restrict__ H = (const uint4*)Hsrc;
    #pragma unroll
    for (int it=0; it<2; ++it){
      int rl   = it*64 + wv*8 + s;
      int node = base + rl;
      uint4 w = make_uint4(0u,0u,0u,0u);
      if (node < n) w = agg_row(H, dinv, offs, csr, bias, node, c8);
      ((uint4*)&Xl[rl*XLD])[c8] = w;
    }
  }

  const int c = lane & 15, g = lane >> 4;
  bfrag wf[2][4];
  #pragma unroll
  for (int kk=0; kk<2; ++kk)
    #pragma unroll
    for (int nt=0; nt<4; ++nt)
      wf[kk][nt] = *((const bfrag*)&WG[((kk*4+g)<<9) + ((nt*16+c)<<3)]);

  __syncthreads();                   // Xl complete

  // ---- phase B: transform, 16 rows/wave ----
  f32x4 acc[4];
  #pragma unroll
  for (int nt=0;nt<4;++nt) acc[nt] = (f32x4){0.f,0.f,0.f,0.f};

  #pragma unroll
  for (int kk=0; kk<2; ++kk){
    bfrag a0 = *((const bfrag*)&Xl[(wv*16 + c)*XLD + kk*32 + g*8]);
    #pragma unroll
    for (int nt=0; nt<4; ++nt)
      acc[nt] = __builtin_amdgcn_mfma_f32_16x16x32_bf16(a0, wf[kk][nt], acc[nt], 0,0,0);
  }

  #pragma unroll
  for (int r=0;r<4;++r){
    int nl   = wv*16 + g*4 + r;
    int node = base + nl;
    if (node < n){
      float dv = Dl[nl];
      #pragma unroll
      for (int nt=0;nt<4;++nt)
        Y[(size_t)node*64 + nt*16 + c] = f2bf(acc[nt][r] * dv);
    }
  }
}

// ---------------- Fused LSTM x2 + heads: 16 rows/wave, zero shuffles (R13, verified) ----------------
__global__ __launch_bounds__(256) void lstm_heads_fused(
    const u16* __restrict__ X,
    const u16* __restrict__ wbuf, const float* __restrict__ bbuf,
    const float* __restrict__ bv1, const float* __restrict__ bv2,
    const float* __restrict__ bt1, const float* __restrict__ bt2,
    float* __restrict__ out, int n)
{
  const u16* W0hi = wbuf;
  const u16* W0lo = wbuf + 6144;
  const u16* W1g  = wbuf + 12288;
  const u16* WHg  = wbuf + 15360;
  const u16* BVg  = wbuf + 17408;
  const u16* BTg  = wbuf + 17920;

  __shared__ u16 Hpool[5120];       // H1hi[0,2560) H1lo[2560,5120); H2 aliases
  __shared__ u16 VT[4608];          // 64 x 72: relu'd [v1|t1]
  __shared__ float b0l[96], b1l[96], bv1l[32], bt1l[32], bt2l[10];
  u16* H1hi = Hpool;  u16* H1lo = Hpool + 2560;
  u16* H2hi = Hpool;  u16* H2lo = Hpool + 2560;

  const int tid  = threadIdx.x;
  const int base = blockIdx.x*64;

  if (tid < 96)            b0l[tid] = bbuf[tid];
  else if (tid < 192)      b1l[tid-96] = bbuf[tid];
  else if (tid < 224){ int d=tid-192; bv1l[d]=bv1[d]; }
  else               { int d=tid-224; bt1l[d]=bt1[d]; }
  if (tid < 10) bt2l[tid] = bt2[tid];
  __syncthreads();

  const int lane = tid & 63, wv = tid >> 6;
  const int c = lane & 15, g = lane >> 4;
  const float bv2v = bv2[0];

  // ---- lstm0: gates = X @ W0^T (K=64, 96 cols) ----
  {
    int r0 = base + wv*16 + c; if (r0 > n-1) r0 = n-1;
    bfrag a0[2];
    a0[0] = *((const bfrag*)(X + (size_t)r0*64      + g*8));
    a0[1] = *((const bfrag*)(X + (size_t)r0*64 + 32 + g*8));
    f32x4 acc[6];
    #pragma unroll
    for (int nt=0;nt<6;++nt) acc[nt] = (f32x4){0.f,0.f,0.f,0.f};
    #pragma unroll
    for (int kk=0; kk<2; ++kk){
      #pragma unroll
      for (int nt=0; nt<6; ++nt){
        int widx = (kk*4+g)*768 + ((nt*16+c)<<3);
        bfrag bh = *((const bfrag*)&W0hi[widx]);
        bfrag bl = *((const bfrag*)&W0lo[widx]);
        acc[nt] = __builtin_amdgcn_mfma_f32_16x16x32_bf16(a0[kk], bh, acc[nt], 0,0,0);
        acc[nt] = __builtin_amdgcn_mfma_f32_16x16x32_bf16(a0[kk], bl, acc[nt], 0,0,0);
      }
    }
    #pragma unroll
    for (int r=0;r<4;++r){
      int rl = wv*16 + g*4 + r;
      #pragma unroll
      for (int half=0; half<2; ++half){
        float iv = acc[0+half][r] + b0l[half*16 + c];
        float gv = acc[2+half][r] + b0l[32 + half*16 + c];
        float ov = acc[4+half][r] + b0l[64 + half*16 + c];
        float cc = fast_sigmoid(iv) * fast_tanh(gv);
        float hv = fast_sigmoid(ov) * fast_tanh(cc);
        u16 hi = f2bf(hv);
        H1hi[rl*40 + half*16 + c] = hi;
        H1lo[rl*40 + half*16 + c] = f2bf(hv - bf2f(hi));
      }
    }
  }
  __syncthreads();                           // H1 visible

  // ---- lstm1: gates = H1 @ W1^T (K=32, 96 cols), A-split 2-term ----
  {
    bfrag w1f[6];
    #pragma unroll
    for (int nt=0; nt<6; ++nt)
      w1f[nt] = *((const bfrag*)&W1g[g*768 + ((nt*16+c)<<3)]);
    bfrag ah = *((const bfrag*)&H1hi[(wv*16 + c)*40 + g*8]);
    bfrag al = *((const bfrag*)&H1lo[(wv*16 + c)*40 + g*8]);
    f32x4 acc[6];
    #pragma unroll
    for (int nt=0;nt<6;++nt) acc[nt] = (f32x4){0.f,0.f,0.f,0.f};
    #pragma unroll
    for (int nt=0; nt<6; ++nt){
      acc[nt] = __builtin_amdgcn_mfma_f32_16x16x32_bf16(ah, w1f[nt], acc[nt], 0,0,0);
      acc[nt] = __builtin_amdgcn_mfma_f32_16x16x32_bf16(al, w1f[nt], acc[nt], 0,0,0);
    }
    __syncthreads();                         // all H1 reads complete before H2 overwrite
    #pragma unroll
    for (int r=0;r<4;++r){
      int rl = wv*16 + g*4 + r;
      #pragma unroll
      for (int half=0; half<2; ++half){
        float iv = acc[0+half][r] + b1l[half*16 + c];
        float gv = acc[2+half][r] + b1l[32 + half*16 + c];
        float ov = acc[4+half][r] + b1l[64 + half*16 + c];
        float cc = fast_sigmoid(iv) * fast_tanh(gv);
        float hv = fast_sigmoid(ov) * fast_tanh(cc);
        u16 hi = f2bf(hv);
        H2hi[rl*40 + half*16 + c] = hi;
        H2lo[rl*40 + half*16 + c] = f2bf(hv - bf2f(hi));
      }
    }
  }
  __syncthreads();                           // H2 visible

  // ---- heads p1: [v1|t1] = relu(H2 @ [Wv1|Wt1] + b) -> VT (bf16) ----
  {
    bfrag whf[4];
    #pragma unroll
    for (int nt=0; nt<4; ++nt)
      whf[nt] = *((const bfrag*)&WHg[g*512 + ((nt*16+c)<<3)]);
    bfrag ah = *((const bfrag*)&H2hi[(wv*16 + c)*40 + g*8]);
    bfrag al = *((const bfrag*)&H2lo[(wv*16 + c)*40 + g*8]);
    f32x4 acc[4];
    #pragma unroll
    for (int nt=0;nt<4;++nt) acc[nt] = (f32x4){0.f,0.f,0.f,0.f};
    #pragma unroll
    for (int nt=0; nt<4; ++nt){
      acc[nt] = __builtin_amdgcn_mfma_f32_16x16x32_bf16(ah, whf[nt], acc[nt], 0,0,0);
      acc[nt] = __builtin_amdgcn_mfma_f32_16x16x32_bf16(al, whf[nt], acc[nt], 0,0,0);
    }
    #pragma unroll
    for (int r=0;r<4;++r){
      int rl = wv*16 + g*4 + r;
      VT[rl*72      + c] = f2bf(fmaxf(acc[0][r] + bv1l[c],    0.f));
      VT[rl*72 + 16 + c] = f2bf(fmaxf(acc[1][r] + bv1l[c+16], 0.f));
      VT[rl*72 + 32 + c] = f2bf(fmaxf(acc[2][r] + bt1l[c],    0.f));
      VT[rl*72 + 48 + c] = f2bf(fmaxf(acc[3][r] + bt1l[c+16], 0.f));
    }
  }
  __syncthreads();                           // VT visible

  // ---- heads p2: vol = v1 @ Wv2, type = t1 @ Wt2 via MFMA, direct C-write ----
  {
    bfrag av = *((const bfrag*)&VT[(wv*16 + c)*72      + g*8]);
    bfrag at = *((const bfrag*)&VT[(wv*16 + c)*72 + 32 + g*8]);
    bfrag bv = *((const bfrag*)(BVg + lane*8));
    bfrag bt = *((const bfrag*)(BTg + lane*8));
    f32x4 accv = (f32x4){0.f,0.f,0.f,0.f};
    f32x4 acct = (f32x4){0.f,0.f,0.f,0.f};
    accv = __builtin_amdgcn_mfma_f32_16x16x32_bf16(av, bv, accv, 0,0,0);
    acct = __builtin_amdgcn_mfma_f32_16x16x32_bf16(at, bt, acct, 0,0,0);
    #pragma unroll
    for (int r=0;r<4;++r){
      int node = base + wv*16 + g*4 + r;
      if (node < n){
        if (c == 0)  out[node] = accv[r] + bv2v;
        if (c < 10)  out[n + (size_t)node*10 + c] = acct[r] + bt2l[c];
      }
    }
  }
}

extern "C" void kernel_launch(void* const* d_in, const int* in_sizes, int n_in,
                              void* d_out, int out_size, void* d_ws, size_t ws_size,
                              hipStream_t stream){
  const float* x    = (const float*)d_in[0];
  const int*   ei   = (const int*)  d_in[1];
  const float* W1   = (const float*)d_in[2];  const float* b1   = (const float*)d_in[3];
  const float* W2   = (const float*)d_in[4];  const float* b2   = (const float*)d_in[5];
  const float* W3   = (const float*)d_in[6];  const float* b3   = (const float*)d_in[7];
  const float* Wih0 = (const float*)d_in[8];
  const float* bih0 = (const float*)d_in[10]; const float* bhh0 = (const float*)d_in[11];
  const float* Wih1 = (const float*)d_in[12];
  const float* bih1 = (const float*)d_in[14]; const float* bhh1 = (const float*)d_in[15];
  const float* Wv1  = (const float*)d_in[16]; const float* bv1  = (const float*)d_in[17];
  const float* Wv2  = (const float*)d_in[18]; const float* bv2  = (const float*)d_in[19];
  const float* Wt1  = (const float*)d_in[20]; const float* bt1  = (const float*)d_in[21];
  const float* Wt2  = (const float*)d_in[22]; const float* bt2  = (const float*)d_in[23];

  const int N  = in_sizes[0] / 128;
  const int E  = in_sizes[1] / 2;
  const int NB = (N + 1023) / 1024;
  const int EB = (E + 8191) / 8192;

  char* w = (char*)d_ws;
  auto take = [&](size_t bytes)->char*{ char* p = w; w += (bytes + 255) & ~(size_t)255; return p; };
  int*   deg    = (int*)  take((size_t)N*4);          // fallback only
  int*   offs   = (int*)  take((size_t)(N+1)*4);
  int*   cursor = (int*)  take((size_t)N*4);          // fallback only
  int*   csr    = (int*)  take((size_t)E*4);
  float* dinv   = (float*)take((size_t)N*4);
  int*   bsums  = (int*)  take((size_t)NB*4);         // fallback only
  int*   boffs  = (int*)  take((size_t)NB*4);         // fallback only
  int*   bhist  = (int*)  take((size_t)MAXBK*4);
  int*   bcur   = (int*)  take((size_t)MAXBK*4);
  int*   bstart = (int*)  take((size_t)(MAXBK+1)*4);
  u32*   packed = (u32*)  take((size_t)E*4);
  u16*   wbuf   = (u16*)  take((size_t)18432*2);      // prepped tail weights + BV/BT frags
  float* bbuf   = (float*)take((size_t)192*4);        // prepped tail biases
  u16*   wgcn   = (u16*)  take((size_t)16384*2);      // prepped GCN weights (bf16 subtiled)
  u16*   bufA   = (u16*)  take((size_t)N*64*2);       // Hts ping
  u16*   bufB   = (u16*)  take((size_t)N*64*2);       // Hts pong
  (void)ws_size; (void)n_in; (void)out_size;

  // --- run-once weight prep (also zeroes bhist) ---
  prep_tail_kernel<<<115, 256, 0, stream>>>(Wih0, Wih1, Wv1, Wt1, Wv2, Wt2,
                                            bih0, bhh0, bih1, bhh1,
                                            W1, W2, W3,
                                            wbuf, bbuf, wgcn, bhist);

  // --- CSR build ---
  if (N <= MAXBK*256){
    const int NBK = (N + 255) / 256;
    bucket_hist_kernel    <<<EB,  512, 0, stream>>>(ei + E, bhist, E);
    bucket_scan_kernel    <<<1,   512, 0, stream>>>(bhist, bcur, bstart);
    bin_kernel            <<<EB,  512, 0, stream>>>(ei, ei + E, bcur, packed, E);
    bucket_finalize_kernel<<<NBK, 512, 0, stream>>>(packed, bstart, offs, dinv, csr, N, E);
  } else {
    hipMemsetAsync(deg, 0, (size_t)N*4, stream);
    count_kernel      <<<(E+255)/256, 256, 0, stream>>>(ei + E, deg, E);
    scan_reduce_kernel<<<NB,          256, 0, stream>>>(deg, bsums, N);
    scan_block_kernel <<<1,           128, 0, stream>>>(bsums, boffs, NB);
    scan_final_kernel <<<NB,          256, 0, stream>>>(deg, boffs, offs, N, E);
    dinv_kernel       <<<(N+255)/256, 256, 0, stream>>>(deg, offs, cursor, dinv, N);
    fill_kernel       <<<(E+255)/256, 256, 0, stream>>>(ei, cursor, csr, E);
  }

  // --- GCN + tail ---
  const int TB  = (N + 127) / 128;
  const int AB  = (N + 31) / 32;
  const int TB2 = (N + 63) / 64;
  transform_mfma<128,float><<<TB, 256, 0, stream>>>(x, wgcn, dinv, bufA, N);
  fused_agg_transform<<<TB, 512, 0, stream>>>(bufA, dinv, offs, csr, b1,
                                              wgcn + 8192,  bufB, N);
  fused_agg_transform<<<TB, 512, 0, stream>>>(bufB, dinv, offs, csr, b2,
                                              wgcn + 12288, bufA, N);
  agg_kernel<<<AB, 256, 0, stream>>>(bufA, dinv, offs, csr, b3, bufB, N);
  lstm_heads_fused<<<TB2, 256, 0, stream>>>(bufB, wbuf, bbuf,
                                            bv1, bv2, bt1, bt2,
                                            (float*)d_out, N);
}

// Round 18
// 181.800 us; speedup vs baseline: 1.0437x; 1.0437x over previous
//
#include <hip/hip_runtime.h>
#include <math.h>

// TemporalWasteGNN: 3x GCNConv (symmetric-norm, self-loops) -> 2x LSTM(seq=1, h0=c0=0)
// -> two MLP heads. fp32 I/O, bf16 intermediate features.
//
// R18: REVERT of R17's 8-deep gather pipeline (regressed 182->190us; gather is
//      memory-system-limited, not chain-depth-limited; extra VGPRs hurt).
//      This is byte-identical to the R16 kernel (measured 182.4us, passed).
// R16 512-thread fused agg+transform, R12 4-deep pipelined gather, R10 packed
// CSR build, R13 prepped slabs, R7 native transcendentals, R13 tail.

typedef unsigned int  u32;
typedef unsigned short u16;
typedef short bfrag  __attribute__((ext_vector_type(8)));   // 8 bf16 (4 VGPRs)
typedef float f32x4  __attribute__((ext_vector_type(4)));

#define LOG2E 1.44269504088896f
static __device__ __forceinline__ float fast_sigmoid(float x){
  float t = __builtin_amdgcn_exp2f(-x * LOG2E);
  return __builtin_amdgcn_rcpf(1.f + t);
}
static __device__ __forceinline__ float fast_tanh(float x){
  float t = __builtin_amdgcn_exp2f(x * (2.f * LOG2E));
  return 1.f - 2.f * __builtin_amdgcn_rcpf(t + 1.f);
}
static __device__ __forceinline__ float bf2f(u16 u){ return __uint_as_float(((u32)u)<<16); }
static __device__ __forceinline__ u16   f2bf(float f){
  u32 x = __float_as_uint(f);
  return (u16)((x + 0x7fffu + ((x>>16)&1u)) >> 16);   // round-to-nearest-even
}

#define MAXBK 512   // buckets of 256 dst nodes; N <= 131072 (src must fit 24 bits)

// ---------------- bucketed CSR build ----------------
__global__ __launch_bounds__(512) void bucket_hist_kernel(const int* __restrict__ dstA,
                                                          int* __restrict__ bhist, int E){
  __shared__ int h[MAXBK];
  for (int i=threadIdx.x; i<MAXBK; i+=512) h[i]=0;
  __syncthreads();
  const int base = blockIdx.x*8192;
  #pragma unroll
  for (int j=0;j<16;++j){
    int e = base + j*512 + threadIdx.x;
    if (e < E) atomicAdd(&h[dstA[e]>>8], 1);
  }
  __syncthreads();
  for (int i=threadIdx.x; i<MAXBK; i+=512) if (h[i]) atomicAdd(&bhist[i], h[i]);
}

__global__ __launch_bounds__(512) void bucket_scan_kernel(const int* __restrict__ bhist,
                                                          int* __restrict__ bcur,
                                                          int* __restrict__ bstart){
  __shared__ int ts[MAXBK];
  int v = bhist[threadIdx.x];
  ts[threadIdx.x] = v; __syncthreads();
  for (int off=1; off<MAXBK; off<<=1){
    int t = (threadIdx.x>=off) ? ts[threadIdx.x-off] : 0;
    __syncthreads();
    ts[threadIdx.x] += t;
    __syncthreads();
  }
  int ex = ts[threadIdx.x] - v;
  bcur[threadIdx.x]   = ex;
  bstart[threadIdx.x] = ex;
  if (threadIdx.x == MAXBK-1) bstart[MAXBK] = ts[threadIdx.x];   // = E
}

__global__ __launch_bounds__(512) void bin_kernel(const int* __restrict__ srcA,
                                                  const int* __restrict__ dstA,
                                                  int* __restrict__ bcur,
                                                  u32* __restrict__ packed, int E){
  __shared__ int h[MAXBK];
  __shared__ int basev[MAXBK];
  for (int i=threadIdx.x; i<MAXBK; i+=512) h[i]=0;
  __syncthreads();
  const int base = blockIdx.x*8192;
  int br[16]; int dv[16];
  #pragma unroll
  for (int j=0;j<16;++j){
    int e = base + j*512 + threadIdx.x;
    if (e < E){
      int d = dstA[e]; int b = d>>8;
      int r = atomicAdd(&h[b], 1);
      br[j] = (b<<16) | r;                 // b<512 (9b) | r<8192 (13b)
      dv[j] = d;
    } else br[j] = -1;
  }
  __syncthreads();
  for (int i=threadIdx.x; i<MAXBK; i+=512){
    int c = h[i];
    basev[i] = c ? atomicAdd(&bcur[i], c) : 0;
  }
  __syncthreads();
  #pragma unroll
  for (int j=0;j<16;++j){
    if (br[j] >= 0){
      int e = base + j*512 + threadIdx.x;
      int pos = basev[br[j]>>16] + (br[j] & 0xffff);
      packed[pos] = (u32)srcA[e] | ((u32)(dv[j] & 255) << 24);
    }
  }
}

__global__ __launch_bounds__(512) void bucket_finalize_kernel(
    const u32* __restrict__ packed, const int* __restrict__ bstart,
    int* __restrict__ offs, float* __restrict__ dinv,
    int* __restrict__ csr, int n, int E){
  __shared__ int cnt[256];
  __shared__ int sc[256];
  __shared__ int cur[256];
  const int b = blockIdx.x;
  const int start = bstart[b], end = bstart[b+1];
  for (int i=threadIdx.x; i<256; i+=512){ cnt[i]=0; cur[i]=0; }
  __syncthreads();
  for (int e = start + threadIdx.x; e < end; e += 512)
    atomicAdd(&cnt[packed[e] >> 24], 1);
  __syncthreads();
  if (threadIdx.x < 256) sc[threadIdx.x] = cnt[threadIdx.x];
  __syncthreads();
  for (int off=1; off<256; off<<=1){
    int t = 0;
    if (threadIdx.x < 256 && threadIdx.x >= off) t = sc[threadIdx.x-off];
    __syncthreads();
    if (threadIdx.x < 256) sc[threadIdx.x] += t;
    __syncthreads();
  }
  if (threadIdx.x < 256){
    int ex = sc[threadIdx.x] - cnt[threadIdx.x];      // exclusive
    sc[threadIdx.x] = ex;
    int node = b*256 + threadIdx.x;
    if (node < n){
      offs[node] = start + ex;
      dinv[node] = rsqrtf((float)(cnt[threadIdx.x] + 1));
    }
  }
  if (b == 0 && threadIdx.x == 0) offs[n] = E;
  __syncthreads();
  for (int e = start + threadIdx.x; e < end; e += 512){
    u32 v = packed[e];
    int loc = v >> 24;
    int pos = start + sc[loc] + atomicAdd(&cur[loc], 1);
    csr[pos] = (int)(v & 0xFFFFFFu);
  }
}

// fallback (N too large for bucketing) -------------
__global__ void count_kernel(const int* __restrict__ dsts, int* __restrict__ deg, int E){
  int e = blockIdx.x*256 + threadIdx.x;
  if (e < E) atomicAdd(&deg[dsts[e]], 1);
}
__global__ void fill_kernel(const int* __restrict__ ei, int* __restrict__ cursor,
                            int* __restrict__ csr, int E){
  int e = blockIdx.x*256 + threadIdx.x;
  if (e < E){
    int d = ei[E + e];
    int pos = atomicAdd(&cursor[d], 1);
    csr[pos] = ei[e];
  }
}

__global__ void scan_reduce_kernel(const int* __restrict__ deg, int* __restrict__ bsums, int n){
  __shared__ int sd[256];
  int base = blockIdx.x*1024 + threadIdx.x*4;
  int s = 0;
  #pragma unroll
  for (int j=0;j<4;++j){ int idx=base+j; if (idx<n) s += deg[idx]; }
  sd[threadIdx.x] = s; __syncthreads();
  for (int off=128; off>0; off>>=1){
    if (threadIdx.x < off) sd[threadIdx.x] += sd[threadIdx.x+off];
    __syncthreads();
  }
  if (threadIdx.x==0) bsums[blockIdx.x] = sd[0];
}

__global__ void scan_block_kernel(const int* __restrict__ bsums, int* __restrict__ boffs, int nb){
  __shared__ int ts[128];
  if (nb <= 128){
    int v = (threadIdx.x < nb) ? bsums[threadIdx.x] : 0;
    ts[threadIdx.x] = v; __syncthreads();
    for (int off=1; off<128; off<<=1){
      int t = (threadIdx.x>=off) ? ts[threadIdx.x-off] : 0;
      __syncthreads();
      ts[threadIdx.x] += t;
      __syncthreads();
    }
    if (threadIdx.x < nb) boffs[threadIdx.x] = ts[threadIdx.x] - v;
  } else if (threadIdx.x==0){
    int run=0;
    for (int b=0;b<nb;++b){ int t=bsums[b]; boffs[b]=run; run+=t; }
  }
}

__global__ void scan_final_kernel(const int* __restrict__ deg, const int* __restrict__ boffs,
                                  int* __restrict__ offs, int n, int E){
  __shared__ int ts[256];
  int base = blockIdx.x*1024 + threadIdx.x*4;
  int v[4]; int s=0;
  #pragma unroll
  for (int j=0;j<4;++j){ int idx=base+j; v[j] = (idx<n) ? deg[idx] : 0; s += v[j]; }
  ts[threadIdx.x] = s; __syncthreads();
  for (int off=1; off<256; off<<=1){
    int t = (threadIdx.x>=off) ? ts[threadIdx.x-off] : 0;
    __syncthreads();
    ts[threadIdx.x] += t;
    __syncthreads();
  }
  int excl = boffs[blockIdx.x] + (threadIdx.x ? ts[threadIdx.x-1] : 0);
  #pragma unroll
  for (int j=0;j<4;++j){ int idx=base+j; if (idx<n){ offs[idx]=excl; excl+=v[j]; } }
  if (blockIdx.x==0 && threadIdx.x==0) offs[n] = E;
}

__global__ void dinv_kernel(const int* __restrict__ deg, const int* __restrict__ offs,
                            int* __restrict__ cursor, float* __restrict__ dinv, int n){
  int i = blockIdx.x*256 + threadIdx.x;
  if (i < n){
    dinv[i] = rsqrtf((float)(deg[i] + 1));
    cursor[i] = offs[i];
  }
}

// ---------------- run-once weight prep (tail + GCN) ----------------
__global__ void prep_tail_kernel(const float* __restrict__ Wih0, const float* __restrict__ Wih1,
                                 const float* __restrict__ Wv1,  const float* __restrict__ Wt1,
                                 const float* __restrict__ Wv2,  const float* __restrict__ Wt2,
                                 const float* __restrict__ bih0, const float* __restrict__ bhh0,
                                 const float* __restrict__ bih1, const float* __restrict__ bhh1,
                                 const float* __restrict__ Wg1,  const float* __restrict__ Wg2,
                                 const float* __restrict__ Wg3,
                                 u16* __restrict__ wbuf, float* __restrict__ bbuf,
                                 u16* __restrict__ wgcn, int* __restrict__ bhist){
  int tid = blockIdx.x*256 + threadIdx.x;
  if (tid < 6144){                                  // Wih0 hi/lo, [k/8][96][8]
    int kg = tid / 768, rem = tid % 768;
    int j = rem >> 3, k = kg*8 + (rem & 7);
    int row = (j < 32) ? j : j + 32;
    float w = Wih0[row*64 + k];
    u16 hi = f2bf(w);
    wbuf[tid] = hi;
    wbuf[6144 + tid] = f2bf(w - bf2f(hi));
  } else if (tid < 9216){                           // Wih1, [k/8][96][8]
    int t = tid - 6144;
    int kg = t / 768, rem = t % 768;
    int j = rem >> 3, k = kg*8 + (rem & 7);
    int row = (j < 32) ? j : j + 32;
    wbuf[12288 + t] = f2bf(Wih1[row*32 + k]);
  } else if (tid < 11264){                          // Wv1|Wt1, [k/8][64][8]
    int t = tid - 9216;
    int kg = t / 512, rem = t % 512;
    int j = rem >> 3, k = kg*8 + (rem & 7);
    float v = (j < 32) ? Wv1[k*32 + j] : Wt1[k*32 + (j-32)];
    wbuf[15360 + t] = f2bf(v);
  } else if (tid < 11360){                          // b0 (i,g,o combined)
    int t = tid - 11264;
    int row = (t < 32) ? t : t + 32;
    bbuf[t] = bih0[row] + bhh0[row];
  } else if (tid < 11456){                          // b1
    int t = tid - 11360;
    int row = (t < 32) ? t : t + 32;
    bbuf[96 + t] = bih1[row] + bhh1[row];
  } else if (tid < 12480){                          // BV/BT lane fragments (K=32)
    int t = tid - 11456;
    int slab = t >> 9, within = t & 511;
    int lane = within >> 3, j = within & 7;
    int cc = lane & 15, gg = lane >> 4;
    float v;
    if (slab == 0) v = (cc == 0) ? Wv2[gg*8 + j] : 0.f;
    else           v = (cc < 10) ? Wt2[(gg*8 + j)*10 + cc] : 0.f;
    wbuf[17408 + slab*512 + within] = f2bf(v);
  } else if (tid < 12992){                          // zero bhist
    bhist[tid - 12480] = 0;
  } else if (tid < 21184){                          // W1 (128x64) -> G1
    int t = tid - 12992;
    int kg = t >> 9, rem = t & 511;
    int j = rem >> 3, k = kg*8 + (rem & 7);
    wgcn[t] = f2bf(Wg1[k*64 + j]);
  } else if (tid < 25280){                          // W2 (64x64) -> G2
    int t = tid - 21184;
    int kg = t >> 9, rem = t & 511;
    int j = rem >> 3, k = kg*8 + (rem & 7);
    wgcn[8192 + t] = f2bf(Wg2[k*64 + j]);
  } else if (tid < 29376){                          // W3 (64x64) -> G3
    int t = tid - 25280;
    int kg = t >> 9, rem = t & 511;
    int j = rem >> 3, k = kg*8 + (rem & 7);
    wgcn[12288 + t] = f2bf(Wg3[k*64 + j]);
  }
}

// ---------------- gather-agg helper: acc over adjacency, 4-deep pipelined ----------------
static __device__ __forceinline__ uint4 agg_row(const uint4* __restrict__ H,
                                                const float* __restrict__ dinv,
                                                const int* __restrict__ offs,
                                                const int* __restrict__ csr,
                                                const float* __restrict__ bias,
                                                int node, int c8){
  float acc[8];
  #pragma unroll
  for (int i=0;i<8;++i) acc[i]=0.f;
  const int beg = offs[node], end = offs[node+1];
  #define ACC8(v) do{ \
    acc[0] += __uint_as_float((v).x<<16); acc[1] += __uint_as_float((v).x & 0xffff0000u); \
    acc[2] += __uint_as_float((v).y<<16); acc[3] += __uint_as_float((v).y & 0xffff0000u); \
    acc[4] += __uint_as_float((v).z<<16); acc[5] += __uint_as_float((v).z & 0xffff0000u); \
    acc[6] += __uint_as_float((v).w<<16); acc[7] += __uint_as_float((v).w & 0xffff0000u); }while(0)
  int j = beg;
  for (; j + 4 <= end; j += 4){
    int s0 = csr[j], s1 = csr[j+1], s2 = csr[j+2], s3 = csr[j+3];
    uint4 v0 = H[(size_t)s0*8 + c8];
    uint4 v1 = H[(size_t)s1*8 + c8];
    uint4 v2 = H[(size_t)s2*8 + c8];
    uint4 v3 = H[(size_t)s3*8 + c8];
    ACC8(v0); ACC8(v1); ACC8(v2); ACC8(v3);
  }
  for (; j < end; ++j){
    int src = csr[j];
    uint4 v = H[(size_t)src*8 + c8];
    ACC8(v);
  }
  #undef ACC8
  uint4 sv = H[(size_t)node*8 + c8];       // self-loop (already * dinv[node])
  float sf[8];
  sf[0]=__uint_as_float(sv.x<<16); sf[1]=__uint_as_float(sv.x & 0xffff0000u);
  sf[2]=__uint_as_float(sv.y<<16); sf[3]=__uint_as_float(sv.y & 0xffff0000u);
  sf[4]=__uint_as_float(sv.z<<16); sf[5]=__uint_as_float(sv.z & 0xffff0000u);
  sf[6]=__uint_as_float(sv.w<<16); sf[7]=__uint_as_float(sv.w & 0xffff0000u);
  float4 b0 = ((const float4*)bias)[c8*2];
  float4 b1 = ((const float4*)bias)[c8*2+1];
  const float dv = dinv[node];
  float o[8];
  o[0]=fmaxf(fmaf(acc[0]+sf[0],dv,b0.x),0.f); o[1]=fmaxf(fmaf(acc[1]+sf[1],dv,b0.y),0.f);
  o[2]=fmaxf(fmaf(acc[2]+sf[2],dv,b0.z),0.f); o[3]=fmaxf(fmaf(acc[3]+sf[3],dv,b0.w),0.f);
  o[4]=fmaxf(fmaf(acc[4]+sf[4],dv,b1.x),0.f); o[5]=fmaxf(fmaf(acc[5]+sf[5],dv,b1.y),0.f);
  o[6]=fmaxf(fmaf(acc[6]+sf[6],dv,b1.z),0.f); o[7]=fmaxf(fmaf(acc[7]+sf[7],dv,b1.w),0.f);
  uint4 w;
  w.x = (u32)f2bf(o[0]) | ((u32)f2bf(o[1])<<16);
  w.y = (u32)f2bf(o[2]) | ((u32)f2bf(o[3])<<16);
  w.z = (u32)f2bf(o[4]) | ((u32)f2bf(o[5])<<16);
  w.w = (u32)f2bf(o[6]) | ((u32)f2bf(o[7])<<16);
  return w;
}

// ---------------- standalone agg (layer 3): 8 nodes/wave, 4-deep pipelined ----------------
__global__ void agg_kernel(const u16* __restrict__ Hts, const float* __restrict__ dinv,
                           const int* __restrict__ offs, const int* __restrict__ csr,
                           const float* __restrict__ bias, u16* __restrict__ Hout, int n){
  const int lane = threadIdx.x & 63;
  const int wv   = threadIdx.x >> 6;
  const int s    = lane >> 3;
  const int c8   = lane & 7;
  const int node = blockIdx.x*32 + wv*8 + s;
  if (node >= n) return;
  const uint4* __restrict__ H = (const uint4*)Hts;
  uint4 w = agg_row(H, dinv, offs, csr, bias, node, c8);
  ((uint4*)Hout)[(size_t)node*8 + c8] = w;
}

// ---------------- GCN transform via MFMA (layer 1; W from prepped slab) ----------------
template<int KD, typename TIN>
__global__ __launch_bounds__(256) void transform_mfma(const TIN* __restrict__ X,
                                                      const u16* __restrict__ WG,
                                                      const float* __restrict__ dinv,
                                                      u16* __restrict__ Y, int n){
  constexpr int XLD = KD + 8;
  __shared__ u16 Xl[128*XLD];
  __shared__ float Dl[128];
  const int tid  = threadIdx.x;
  const int base = blockIdx.x*128;

  if (tid < 128){
    int nd = base + tid;
    Dl[tid] = (nd < n) ? dinv[nd] : 0.f;
  }
  if constexpr (sizeof(TIN)==4){
    #pragma unroll
    for (int j = 0; j < (128*KD)/1024; ++j){
      int e4   = tid + j*256;
      int elem = e4*4;
      int row  = elem / KD, k = elem % KD;
      int gn   = base + row;
      uint2 w2 = make_uint2(0u, 0u);
      if (gn < n){
        float4 v = ((const float4*)X)[(size_t)gn*(KD/4) + (k>>2)];
        w2.x = (u32)f2bf(v.x) | ((u32)f2bf(v.y)<<16);
        w2.y = (u32)f2bf(v.z) | ((u32)f2bf(v.w)<<16);
      }
      *((uint2*)&Xl[row*XLD + k]) = w2;
    }
  } else {
    #pragma unroll
    for (int j = 0; j < (128*KD)/1024; ++j){
      int e4   = tid + j*256;
      int elem = e4*4;
      int row  = elem / KD, k = elem % KD;
      int gn   = base + row;
      uint2 v = make_uint2(0u, 0u);
      if (gn < n) v = *((const uint2*)(X + (size_t)gn*KD + k));
      *((uint2*)&Xl[row*XLD + k]) = v;
    }
  }

  const int lane = tid & 63, wv = tid >> 6;
  const int c = lane & 15, g = lane >> 4;

  bfrag wf[KD/32][4];
  #pragma unroll
  for (int kk=0; kk<KD/32; ++kk)
    #pragma unroll
    for (int nt=0; nt<4; ++nt)
      wf[kk][nt] = *((const bfrag*)&WG[((kk*4+g)<<9) + ((nt*16+c)<<3)]);

  __syncthreads();                   // Xl ready

  f32x4 acc[2][4];
  #pragma unroll
  for (int rs=0;rs<2;++rs)
    #pragma unroll
    for (int nt=0;nt<4;++nt)
      acc[rs][nt] = (f32x4){0.f,0.f,0.f,0.f};

  #pragma unroll
  for (int kk=0; kk<KD/32; ++kk){
    bfrag a0 = *((const bfrag*)&Xl[(wv*32      + c)*XLD + kk*32 + g*8]);
    bfrag a1 = *((const bfrag*)&Xl[(wv*32 + 16 + c)*XLD + kk*32 + g*8]);
    #pragma unroll
    for (int nt=0; nt<4; ++nt){
      acc[0][nt] = __builtin_amdgcn_mfma_f32_16x16x32_bf16(a0, wf[kk][nt], acc[0][nt], 0,0,0);
      acc[1][nt] = __builtin_amdgcn_mfma_f32_16x16x32_bf16(a1, wf[kk][nt], acc[1][nt], 0,0,0);
    }
  }

  #pragma unroll
  for (int rs=0;rs<2;++rs){
    int nl0 = wv*32 + rs*16 + g*4;
    #pragma unroll
    for (int r=0;r<4;++r){
      int node = base + nl0 + r;
      if (node < n){
        float dv = Dl[nl0 + r];
        #pragma unroll
        for (int nt=0;nt<4;++nt)
          Y[(size_t)node*64 + nt*16 + c] = f2bf(acc[rs][nt][r] * dv);
      }
    }
  }
}

// ---------------- fused agg + transform (layers 2,3 input), 512 threads ----------------
__global__ __launch_bounds__(512) void fused_agg_transform(
    const u16* __restrict__ Hsrc, const float* __restrict__ dinv,
    const int* __restrict__ offs, const int* __restrict__ csr,
    const float* __restrict__ bias, const u16* __restrict__ WG,
    u16* __restrict__ Y, int n){
  constexpr int XLD = 72;
  __shared__ u16 Xl[128*XLD];
  __shared__ float Dl[128];
  const int tid  = threadIdx.x;
  const int base = blockIdx.x*128;
  const int lane = tid & 63, wv = tid >> 6;   // wv in 0..7

  if (tid < 128){
    int nd = base + tid;
    Dl[tid] = (nd < n) ? dinv[nd] : 0.f;
  }

  // ---- phase A: aggregate this block's 128 nodes into Xl ----
  {
    const int s  = lane >> 3;
    const int c8 = lane & 7;
    const uint4* __restrict__ H = (const uint4*)Hsrc;
    #pragma unroll
    for (int it=0; it<2; ++it){
      int rl   = it*64 + wv*8 + s;
      int node = base + rl;
      uint4 w = make_uint4(0u,0u,0u,0u);
      if (node < n) w = agg_row(H, dinv, offs, csr, bias, node, c8);
      ((uint4*)&Xl[rl*XLD])[c8] = w;
    }
  }

  const int c = lane & 15, g = lane >> 4;
  bfrag wf[2][4];
  #pragma unroll
  for (int kk=0; kk<2; ++kk)
    #pragma unroll
    for (int nt=0; nt<4; ++nt)
      wf[kk][nt] = *((const bfrag*)&WG[((kk*4+g)<<9) + ((nt*16+c)<<3)]);

  __syncthreads();                   // Xl complete

  // ---- phase B: transform, 16 rows/wave ----
  f32x4 acc[4];
  #pragma unroll
  for (int nt=0;nt<4;++nt) acc[nt] = (f32x4){0.f,0.f,0.f,0.f};

  #pragma unroll
  for (int kk=0; kk<2; ++kk){
    bfrag a0 = *((const bfrag*)&Xl[(wv*16 + c)*XLD + kk*32 + g*8]);
    #pragma unroll
    for (int nt=0; nt<4; ++nt)
      acc[nt] = __builtin_amdgcn_mfma_f32_16x16x32_bf16(a0, wf[kk][nt], acc[nt], 0,0,0);
  }

  #pragma unroll
  for (int r=0;r<4;++r){
    int nl   = wv*16 + g*4 + r;
    int node = base + nl;
    if (node < n){
      float dv = Dl[nl];
      #pragma unroll
      for (int nt=0;nt<4;++nt)
        Y[(size_t)node*64 + nt*16 + c] = f2bf(acc[nt][r] * dv);
    }
  }
}

// ---------------- Fused LSTM x2 + heads: 16 rows/wave, zero shuffles (R13, verified) ----------------
__global__ __launch_bounds__(256) void lstm_heads_fused(
    const u16* __restrict__ X,
    const u16* __restrict__ wbuf, const float* __restrict__ bbuf,
    const float* __restrict__ bv1, const float* __restrict__ bv2,
    const float* __restrict__ bt1, const float* __restrict__ bt2,
    float* __restrict__ out, int n)
{
  const u16* W0hi = wbuf;
  const u16* W0lo = wbuf + 6144;
  const u16* W1g  = wbuf + 12288;
  const u16* WHg  = wbuf + 15360;
  const u16* BVg  = wbuf + 17408;
  const u16* BTg  = wbuf + 17920;

  __shared__ u16 Hpool[5120];       // H1hi[0,2560) H1lo[2560,5120); H2 aliases
  __shared__ u16 VT[4608];          // 64 x 72: relu'd [v1|t1]
  __shared__ float b0l[96], b1l[96], bv1l[32], bt1l[32], bt2l[10];
  u16* H1hi = Hpool;  u16* H1lo = Hpool + 2560;
  u16* H2hi = Hpool;  u16* H2lo = Hpool + 2560;

  const int tid  = threadIdx.x;
  const int base = blockIdx.x*64;

  if (tid < 96)            b0l[tid] = bbuf[tid];
  else if (tid < 192)      b1l[tid-96] = bbuf[tid];
  else if (tid < 224){ int d=tid-192; bv1l[d]=bv1[d]; }
  else               { int d=tid-224; bt1l[d]=bt1[d]; }
  if (tid < 10) bt2l[tid] = bt2[tid];
  __syncthreads();

  const int lane = tid & 63, wv = tid >> 6;
  const int c = lane & 15, g = lane >> 4;
  const float bv2v = bv2[0];

  // ---- lstm0: gates = X @ W0^T (K=64, 96 cols) ----
  {
    int r0 = base + wv*16 + c; if (r0 > n-1) r0 = n-1;
    bfrag a0[2];
    a0[0] = *((const bfrag*)(X + (size_t)r0*64      + g*8));
    a0[1] = *((const bfrag*)(X + (size_t)r0*64 + 32 + g*8));
    f32x4 acc[6];
    #pragma unroll
    for (int nt=0;nt<6;++nt) acc[nt] = (f32x4){0.f,0.f,0.f,0.f};
    #pragma unroll
    for (int kk=0; kk<2; ++kk){
      #pragma unroll
      for (int nt=0; nt<6; ++nt){
        int widx = (kk*4+g)*768 + ((nt*16+c)<<3);
        bfrag bh = *((const bfrag*)&W0hi[widx]);
        bfrag bl = *((const bfrag*)&W0lo[widx]);
        acc[nt] = __builtin_amdgcn_mfma_f32_16x16x32_bf16(a0[kk], bh, acc[nt], 0,0,0);
        acc[nt] = __builtin_amdgcn_mfma_f32_16x16x32_bf16(a0[kk], bl, acc[nt], 0,0,0);
      }
    }
    #pragma unroll
    for (int r=0;r<4;++r){
      int rl = wv*16 + g*4 + r;
      #pragma unroll
      for (int half=0; half<2; ++half){
        float iv = acc[0+half][r] + b0l[half*16 + c];
        float gv = acc[2+half][r] + b0l[32 + half*16 + c];
        float ov = acc[4+half][r] + b0l[64 + half*16 + c];
        float cc = fast_sigmoid(iv) * fast_tanh(gv);
        float hv = fast_sigmoid(ov) * fast_tanh(cc);
        u16 hi = f2bf(hv);
        H1hi[rl*40 + half*16 + c] = hi;
        H1lo[rl*40 + half*16 + c] = f2bf(hv - bf2f(hi));
      }
    }
  }
  __syncthreads();                           // H1 visible

  // ---- lstm1: gates = H1 @ W1^T (K=32, 96 cols), A-split 2-term ----
  {
    bfrag w1f[6];
    #pragma unroll
    for (int nt=0; nt<6; ++nt)
      w1f[nt] = *((const bfrag*)&W1g[g*768 + ((nt*16+c)<<3)]);
    bfrag ah = *((const bfrag*)&H1hi[(wv*16 + c)*40 + g*8]);
    bfrag al = *((const bfrag*)&H1lo[(wv*16 + c)*40 + g*8]);
    f32x4 acc[6];
    #pragma unroll
    for (int nt=0;nt<6;++nt) acc[nt] = (f32x4){0.f,0.f,0.f,0.f};
    #pragma unroll
    for (int nt=0; nt<6; ++nt){
      acc[nt] = __builtin_amdgcn_mfma_f32_16x16x32_bf16(ah, w1f[nt], acc[nt], 0,0,0);
      acc[nt] = __builtin_amdgcn_mfma_f32_16x16x32_bf16(al, w1f[nt], acc[nt], 0,0,0);
    }
    __syncthreads();                         // all H1 reads complete before H2 overwrite
    #pragma unroll
    for (int r=0;r<4;++r){
      int rl = wv*16 + g*4 + r;
      #pragma unroll
      for (int half=0; half<2; ++half){
        float iv = acc[0+half][r] + b1l[half*16 + c];
        float gv = acc[2+half][r] + b1l[32 + half*16 + c];
        float ov = acc[4+half][r] + b1l[64 + half*16 + c];
        float cc = fast_sigmoid(iv) * fast_tanh(gv);
        float hv = fast_sigmoid(ov) * fast_tanh(cc);
        u16 hi = f2bf(hv);
        H2hi[rl*40 + half*16 + c] = hi;
        H2lo[rl*40 + half*16 + c] = f2bf(hv - bf2f(hi));
      }
    }
  }
  __syncthreads();                           // H2 visible

  // ---- heads p1: [v1|t1] = relu(H2 @ [Wv1|Wt1] + b) -> VT (bf16) ----
  {
    bfrag whf[4];
    #pragma unroll
    for (int nt=0; nt<4; ++nt)
      whf[nt] = *((const bfrag*)&WHg[g*512 + ((nt*16+c)<<3)]);
    bfrag ah = *((const bfrag*)&H2hi[(wv*16 + c)*40 + g*8]);
    bfrag al = *((const bfrag*)&H2lo[(wv*16 + c)*40 + g*8]);
    f32x4 acc[4];
    #pragma unroll
    for (int nt=0;nt<4;++nt) acc[nt] = (f32x4){0.f,0.f,0.f,0.f};
    #pragma unroll
    for (int nt=0; nt<4; ++nt){
      acc[nt] = __builtin_amdgcn_mfma_f32_16x16x32_bf16(ah, whf[nt], acc[nt], 0,0,0);
      acc[nt] = __builtin_amdgcn_mfma_f32_16x16x32_bf16(al, whf[nt], acc[nt], 0,0,0);
    }
    #pragma unroll
    for (int r=0;r<4;++r){
      int rl = wv*16 + g*4 + r;
      VT[rl*72      + c] = f2bf(fmaxf(acc[0][r] + bv1l[c],    0.f));
      VT[rl*72 + 16 + c] = f2bf(fmaxf(acc[1][r] + bv1l[c+16], 0.f));
      VT[rl*72 + 32 + c] = f2bf(fmaxf(acc[2][r] + bt1l[c],    0.f));
      VT[rl*72 + 48 + c] = f2bf(fmaxf(acc[3][r] + bt1l[c+16], 0.f));
    }
  }
  __syncthreads();                           // VT visible

  // ---- heads p2: vol = v1 @ Wv2, type = t1 @ Wt2 via MFMA, direct C-write ----
  {
    bfrag av = *((const bfrag*)&VT[(wv*16 + c)*72      + g*8]);
    bfrag at = *((const bfrag*)&VT[(wv*16 + c)*72 + 32 + g*8]);
    bfrag bv = *((const bfrag*)(BVg + lane*8));
    bfrag bt = *((const bfrag*)(BTg + lane*8));
    f32x4 accv = (f32x4){0.f,0.f,0.f,0.f};
    f32x4 acct = (f32x4){0.f,0.f,0.f,0.f};
    accv = __builtin_amdgcn_mfma_f32_16x16x32_bf16(av, bv, accv, 0,0,0);
    acct = __builtin_amdgcn_mfma_f32_16x16x32_bf16(at, bt, acct, 0,0,0);
    #pragma unroll
    for (int r=0;r<4;++r){
      int node = base + wv*16 + g*4 + r;
      if (node < n){
        if (c == 0)  out[node] = accv[r] + bv2v;
        if (c < 10)  out[n + (size_t)node*10 + c] = acct[r] + bt2l[c];
      }
    }
  }
}

extern "C" void kernel_launch(void* const* d_in, const int* in_sizes, int n_in,
                              void* d_out, int out_size, void* d_ws, size_t ws_size,
                              hipStream_t stream){
  const float* x    = (const float*)d_in[0];
  const int*   ei   = (const int*)  d_in[1];
  const float* W1   = (const float*)d_in[2];  const float* b1   = (const float*)d_in[3];
  const float* W2   = (const float*)d_in[4];  const float* b2   = (const float*)d_in[5];
  const float* W3   = (const float*)d_in[6];  const float* b3   = (const float*)d_in[7];
  const float* Wih0 = (const float*)d_in[8];
  const float* bih0 = (const float*)d_in[10]; const float* bhh0 = (const float*)d_in[11];
  const float* Wih1 = (const float*)d_in[12];
  const float* bih1 = (const float*)d_in[14]; const float* bhh1 = (const float*)d_in[15];
  const float* Wv1  = (const float*)d_in[16]; const float* bv1  = (const float*)d_in[17];
  const float* Wv2  = (const float*)d_in[18]; const float* bv2  = (const float*)d_in[19];
  const float* Wt1  = (const float*)d_in[20]; const float* bt1  = (const float*)d_in[21];
  const float* Wt2  = (const float*)d_in[22]; const float* bt2  = (const float*)d_in[23];

  const int N  = in_sizes[0] / 128;
  const int E  = in_sizes[1] / 2;
  const int NB = (N + 1023) / 1024;
  const int EB = (E + 8191) / 8192;

  char* w = (char*)d_ws;
  auto take = [&](size_t bytes)->char*{ char* p = w; w += (bytes + 255) & ~(size_t)255; return p; };
  int*   deg    = (int*)  take((size_t)N*4);          // fallback only
  int*   offs   = (int*)  take((size_t)(N+1)*4);
  int*   cursor = (int*)  take((size_t)N*4);          // fallback only
  int*   csr    = (int*)  take((size_t)E*4);
  float* dinv   = (float*)take((size_t)N*4);
  int*   bsums  = (int*)  take((size_t)NB*4);         // fallback only
  int*   boffs  = (int*)  take((size_t)NB*4);         // fallback only
  int*   bhist  = (int*)  take((size_t)MAXBK*4);
  int*   bcur   = (int*)  take((size_t)MAXBK*4);
  int*   bstart = (int*)  take((size_t)(MAXBK+1)*4);
  u32*   packed = (u32*)  take((size_t)E*4);
  u16*   wbuf   = (u16*)  take((size_t)18432*2);      // prepped tail weights + BV/BT frags
  float* bbuf   = (float*)take((size_t)192*4);        // prepped tail biases
  u16*   wgcn   = (u16*)  take((size_t)16384*2);      // prepped GCN weights (bf16 subtiled)
  u16*   bufA   = (u16*)  take((size_t)N*64*2);       // Hts ping
  u16*   bufB   = (u16*)  take((size_t)N*64*2);       // Hts pong
  (void)ws_size; (void)n_in; (void)out_size;

  // --- run-once weight prep (also zeroes bhist) ---
  prep_tail_kernel<<<115, 256, 0, stream>>>(Wih0, Wih1, Wv1, Wt1, Wv2, Wt2,
                                            bih0, bhh0, bih1, bhh1,
                                            W1, W2, W3,
                                            wbuf, bbuf, wgcn, bhist);

  // --- CSR build ---
  if (N <= MAXBK*256){
    const int NBK = (N + 255) / 256;
    bucket_hist_kernel    <<<EB,  512, 0, stream>>>(ei + E, bhist, E);
    bucket_scan_kernel    <<<1,   512, 0, stream>>>(bhist, bcur, bstart);
    bin_kernel            <<<EB,  512, 0, stream>>>(ei, ei + E, bcur, packed, E);
    bucket_finalize_kernel<<<NBK, 512, 0, stream>>>(packed, bstart, offs, dinv, csr, N, E);
  } else {
    hipMemsetAsync(deg, 0, (size_t)N*4, stream);
    count_kernel      <<<(E+255)/256, 256, 0, stream>>>(ei + E, deg, E);
    scan_reduce_kernel<<<NB,          256, 0, stream>>>(deg, bsums, N);
    scan_block_kernel <<<1,           128, 0, stream>>>(bsums, boffs, NB);
    scan_final_kernel <<<NB,          256, 0, stream>>>(deg, boffs, offs, N, E);
    dinv_kernel       <<<(N+255)/256, 256, 0, stream>>>(deg, offs, cursor, dinv, N);
    fill_kernel       <<<(E+255)/256, 256, 0, stream>>>(ei, cursor, csr, E);
  }

  // --- GCN + tail ---
  const int TB  = (N + 127) / 128;
  const int AB  = (N + 31) / 32;
  const int TB2 = (N + 63) / 64;
  transform_mfma<128,float><<<TB, 256, 0, stream>>>(x, wgcn, dinv, bufA, N);
  fused_agg_transform<<<TB, 512, 0, stream>>>(bufA, dinv, offs, csr, b1,
                                              wgcn + 8192,  bufB, N);
  fused_agg_transform<<<TB, 512, 0, stream>>>(bufB, dinv, offs, csr, b2,
                                              wgcn + 12288, bufA, N);
  agg_kernel<<<AB, 256, 0, stream>>>(bufA, dinv, offs, csr, b3, bufB, N);
  lstm_heads_fused<<<TB2, 256, 0, stream>>>(bufB, wbuf, bbuf,
                                            bv1, bv2, bt1, bt2,
                                            (float*)d_out, N);
}